// Round 10
// baseline (388.005 us; speedup 1.0000x reference)
//
#include <hip/hip_runtime.h>

// ---------------------------------------------------------------------------
// EncoderLayer: x -> MHA(entmax1.5) -> +LN -> FFN(mish) -> +LN
// B=8 S=1024 D=512 H=8 hd=64 F=2048.  bf16 MFMA GEMMs, fp32 accum/epilogues.
// Round 10: (a) transposed-operand GEMMs — A=weight side, store C^T so each
// lane's 4 consecutive C-rows pack into ushort4/float4 stores (64 scalar
// stores -> 16 packed); (b) entmax 2 rows/wave, 32 lanes/row (5-stage
// butterfly shared by both rows, per-half ballot counts).
// ---------------------------------------------------------------------------

typedef float f32x4 __attribute__((ext_vector_type(4)));
typedef float f32x2 __attribute__((ext_vector_type(2)));
typedef __bf16 b8 __attribute__((ext_vector_type(8)));

#define DEV static __device__ __forceinline__

DEV unsigned short f2bf(float f) {
  unsigned u = __float_as_uint(f);
  u += 0x7fffu + ((u >> 16) & 1u);   // RNE
  return (unsigned short)(u >> 16);
}
DEV float bf2f(unsigned short b) { return __uint_as_float(((unsigned)b) << 16); }

DEV float mishf(float x) {
  if (x > 20.f) return x;
  float e = __expf(x);
  float u = 1.f + e;
  u *= u;
  return x * ((u - 1.f) / (u + 1.f));
}

DEV void async16(const void* g, void* l) {
  __builtin_amdgcn_global_load_lds(
      (const __attribute__((address_space(1))) unsigned int*)g,
      (__attribute__((address_space(3))) unsigned int*)l, 16, 0, 0);
}

// ---------------------------------------------------------------------------
// MFMA GEMM, BK=64, transposed store (CT): computes C[row][col] = alpha *
// A[row,:]·Bt[col,:] (+bias[row]) (+mish) and stores to out[col][row] --
// lane's r=0..3 are consecutive addresses -> ushort4 / float4 stores.
// Batched / split-K via blockIdx.z: off = (z/hdiv)*s1 + (z%hdiv)*s2.
// ---------------------------------------------------------------------------
template <int WM, int WN, int EPI, bool OUTBF>
__global__ __launch_bounds__(256) void gemm_bt(
    const unsigned short* __restrict__ A, const unsigned short* __restrict__ Bt,
    const float* __restrict__ bias, void* __restrict__ Cp,
    int K, int lda, int ldb, int ldc,
    long sA1, long sA2, long sB1, long sB2, long sC1, long sC2,
    int hdiv, float alpha) {
  constexpr int BM = WM * 64, BN = WN * 64;
  constexpr int NA = WM * 2, NB = WN * 2;
  __shared__ unsigned short smA[BM * 64];
  __shared__ unsigned short smB[BN * 64];

  const int tid = threadIdx.x;
  const int lane = tid & 63;
  const int z = blockIdx.z;
  const long zi = z / hdiv, zr = z % hdiv;
  const unsigned short* Ab = A + zi * sA1 + zr * sA2 + (long)blockIdx.x * BM * lda;
  const unsigned short* Bb = Bt + zi * sB1 + zr * sB2 + (long)blockIdx.y * BN * ldb;

  int siA[NA];
  const unsigned short* gA[NA];
#pragma unroll
  for (int q = 0; q < NA; ++q) {
    int si = q * 256 + tid;
    int m = si >> 3, s = si & 7, g = s ^ (m & 7);
    siA[q] = si;
    gA[q] = Ab + (long)m * lda + g * 8;
  }
  int siB[NB];
  const unsigned short* gB[NB];
#pragma unroll
  for (int q = 0; q < NB; ++q) {
    int si = q * 256 + tid;
    int m = si >> 3, s = si & 7, g = s ^ (m & 7);
    siB[q] = si;
    gB[q] = Bb + (long)m * ldb + g * 8;
  }

  const int w = tid >> 6;
  const int wr = w / WN, wc = w % WN;
  const int fm = lane & 15, fg = lane >> 4;

  int aOff[4][2], bOff[4][2];
#pragma unroll
  for (int i = 0; i < 4; ++i)
#pragma unroll
    for (int ks = 0; ks < 2; ++ks) {
      int m = wr * 64 + i * 16 + fm;
      aOff[i][ks] = (m * 8 + ((ks * 4 + fg) ^ (fm & 7))) * 8;
      int n = wc * 64 + i * 16 + fm;
      bOff[i][ks] = (n * 8 + ((ks * 4 + fg) ^ (fm & 7))) * 8;
    }

  f32x4 acc[4][4];
#pragma unroll
  for (int i = 0; i < 4; ++i)
#pragma unroll
    for (int j = 0; j < 4; ++j) acc[i][j] = (f32x4){0.f, 0.f, 0.f, 0.f};

  for (int k0 = 0; k0 < K; k0 += 64) {
    __syncthreads();
#pragma unroll
    for (int q = 0; q < NA; ++q) async16(gA[q] + k0, (void*)&smA[siA[q] * 8]);
#pragma unroll
    for (int q = 0; q < NB; ++q) async16(gB[q] + k0, (void*)&smB[siB[q] * 8]);
    __syncthreads();  // implies vmcnt(0): staging complete

#pragma unroll
    for (int ks = 0; ks < 2; ++ks) {
      b8 aF[4], bF[4];
#pragma unroll
      for (int i = 0; i < 4; ++i) aF[i] = *(const b8*)&smA[aOff[i][ks]];
#pragma unroll
      for (int j = 0; j < 4; ++j) bF[j] = *(const b8*)&smB[bOff[j][ks]];
#pragma unroll
      for (int i = 0; i < 4; ++i)
#pragma unroll
        for (int j = 0; j < 4; ++j)
          acc[i][j] = __builtin_amdgcn_mfma_f32_16x16x32_bf16(aF[i], bF[j], acc[i][j], 0, 0, 0);
    }
  }

  // transposed epilogue: out[col][rowb..rowb+3] <- acc[i][j][0..3]
  const long cbase = zi * sC1 + zr * sC2;
  const int row0 = blockIdx.x * BM + wr * 64 + fg * 4;
  const int col0 = blockIdx.y * BN + wc * 64 + fm;
#pragma unroll
  for (int i = 0; i < 4; ++i) {
    const int rowb = row0 + i * 16;
    float4 bb = make_float4(0.f, 0.f, 0.f, 0.f);
    if (EPI >= 1) bb = *(const float4*)&bias[rowb];
#pragma unroll
    for (int j = 0; j < 4; ++j) {
      const int col = col0 + j * 16;
      const long idx = cbase + (long)col * ldc + rowb;
      float v0 = acc[i][j][0] * alpha + bb.x;
      float v1 = acc[i][j][1] * alpha + bb.y;
      float v2 = acc[i][j][2] * alpha + bb.z;
      float v3 = acc[i][j][3] * alpha + bb.w;
      if (EPI == 2) {
        v0 = mishf(v0);
        v1 = mishf(v1);
        v2 = mishf(v2);
        v3 = mishf(v3);
      }
      if constexpr (OUTBF) {
        ushort4 pk;
        pk.x = f2bf(v0);
        pk.y = f2bf(v1);
        pk.z = f2bf(v2);
        pk.w = f2bf(v3);
        *(ushort4*)&((unsigned short*)Cp)[idx] = pk;
      } else {
        float4 fv = make_float4(v0, v1, v2, v3);
        *(float4*)&((float*)Cp)[idx] = fv;
      }
    }
  }
}

// ---------------------------------------------------------------------------
// entmax 1.5 over rows of 1024 (in-place bf16). 2 rows per wave, 32 lanes per
// row (lane<32 -> row A, else row B): 5-stage butterfly serves both rows,
// ballot popcounts split low/high 32 bits. Closed-form support iteration,
// stop when BOTH supports are fixed points (wave-uniform). Post-convergence
// re-updates of an already-stable row move tau by ~1e-7 (harmless).
// ---------------------------------------------------------------------------
__global__ __launch_bounds__(256) void entmax_rows(unsigned short* __restrict__ P) {
  const int tid = threadIdx.x, lane = tid & 63, wv = tid >> 6;
  const int half = lane >> 5, l5 = lane & 31;
  const long row = (long)blockIdx.x * 8 + wv * 2 + half;
  unsigned short* p = P + row * 1024 + l5 * 32;

  union { uint4 v; unsigned short u[8]; } t[4];
#pragma unroll
  for (int q = 0; q < 4; ++q) t[q].v = *(const uint4*)(p + q * 8);
  f32x2 zp[16];
#pragma unroll
  for (int q = 0; q < 4; ++q)
#pragma unroll
    for (int i = 0; i < 4; ++i)
      zp[q * 4 + i] = (f32x2){bf2f(t[q].u[2 * i]), bf2f(t[q].u[2 * i + 1])};

  f32x2 mv = zp[0];
#pragma unroll
  for (int i = 1; i < 16; ++i) mv = __builtin_elementwise_max(mv, zp[i]);
  float m = fmaxf(mv.x, mv.y);
#pragma unroll
  for (int o = 16; o; o >>= 1) m = fmaxf(m, __shfl_xor(m, o));  // within half

  float tau = m - 1.f;
  int kApr = -1, kBpr = -1;
  const f32x2 zero2 = (f32x2){0.f, 0.f};
  for (int it = 0; it < 12; ++it) {
    const f32x2 t2 = (f32x2){tau, tau};
    f32x2 s1v = zero2, s2v = zero2;
    int ka = 0, kb = 0;
#pragma unroll
    for (int i = 0; i < 16; ++i) {
      f32x2 h = zp[i] - t2;
      unsigned long long b0 = __ballot(h.x > 0.f);
      unsigned long long b1 = __ballot(h.y > 0.f);
      ka += __popc((unsigned)b0) + __popc((unsigned)b1);
      kb += __popc((unsigned)(b0 >> 32)) + __popc((unsigned)(b1 >> 32));
      f32x2 hp = __builtin_elementwise_max(h, zero2);
      s1v += hp;
      s2v += hp * hp;
    }
    float s1 = s1v.x + s1v.y, s2 = s2v.x + s2v.y;
#pragma unroll
    for (int o = 16; o; o >>= 1) {  // per-half reduction
      s1 += __shfl_xor(s1, o);
      s2 += __shfl_xor(s2, o);
    }
    if (ka == kApr && kb == kBpr) break;  // both supports stable (wave-uniform)
    kApr = ka;
    kBpr = kb;
    float kf = (float)(half ? kb : ka);
    float disc = fmaxf(fmaf(s1, s1, -kf * (s2 - 1.f)), 0.f);
    tau += (s1 - __builtin_sqrtf(disc)) / kf;
  }

  const f32x2 t2 = (f32x2){tau, tau};
#pragma unroll
  for (int q = 0; q < 4; ++q) {
#pragma unroll
    for (int i = 0; i < 4; ++i) {
      f32x2 h = __builtin_elementwise_max(zp[q * 4 + i] - t2, zero2);
      f32x2 pr = h * h;
      t[q].u[2 * i] = f2bf(pr.x);
      t[q].u[2 * i + 1] = f2bf(pr.y);
    }
    *(uint4*)(p + q * 8) = t[q].v;
  }
}

// ---------------------------------------------------------------------------
// Merged prep: x cast + 6 weight transposes + bias concat in ONE launch.
// ---------------------------------------------------------------------------
__global__ __launch_bounds__(256) void prep_all(
    const float* __restrict__ x, unsigned short* __restrict__ xb,
    const float* __restrict__ Wq, const float* __restrict__ Wk,
    const float* __restrict__ Wv, const float* __restrict__ Wo,
    const float* __restrict__ W1, const float* __restrict__ W2,
    unsigned short* __restrict__ Wqkvt, unsigned short* __restrict__ Wot,
    unsigned short* __restrict__ W1t, unsigned short* __restrict__ W2t,
    const float* __restrict__ bq, const float* __restrict__ bk,
    const float* __restrict__ bv, float* __restrict__ bqkv) {
  __shared__ float t[32][33];
  const int bid = blockIdx.x, tid = threadIdx.x;

  if (bid < 4096) {  // cast x -> bf16, 4 elems/thread
    long i = ((long)bid * 256 + tid) * 4;
    float4 v = *(const float4*)&x[i];
    uint2 pk;
    pk.x = (unsigned)f2bf(v.x) | ((unsigned)f2bf(v.y) << 16);
    pk.y = (unsigned)f2bf(v.z) | ((unsigned)f2bf(v.w) << 16);
    *(uint2*)&xb[i] = pk;
    return;
  }

  const float* in;
  unsigned short* out;
  int ldi, ldo, bx, by;
  if (bid < 5120) {
    int t4 = (bid - 4096) >> 8, local = (bid - 4096) & 255;
    const float* ins[4] = {Wq, Wk, Wv, Wo};
    unsigned short* outs[4] = {Wqkvt, Wqkvt + 512 * 512, Wqkvt + 2 * 512 * 512, Wot};
    in = ins[t4];
    out = outs[t4];
    ldi = 512;
    ldo = 512;
    bx = local & 15;
    by = local >> 4;
  } else if (bid < 6144) {
    int local = bid - 5120;  // W1 [512][2048] -> W1t [2048][512]
    in = W1;
    out = W1t;
    ldi = 2048;
    ldo = 512;
    bx = local & 63;
    by = local >> 6;
  } else if (bid < 7168) {
    int local = bid - 6144;  // W2 [2048][512] -> W2t [512][2048]
    in = W2;
    out = W2t;
    ldi = 512;
    ldo = 2048;
    bx = local & 15;
    by = local >> 4;
  } else {  // concat biases
    int i = (bid - 7168) * 256 + tid;
    if (i < 512) bqkv[i] = bq[i];
    else if (i < 1024) bqkv[i] = bk[i - 512];
    else if (i < 1536) bqkv[i] = bv[i - 1024];
    return;
  }

  const int tx = tid & 31, ty = tid >> 5;
  const int r0 = by * 32, c0 = bx * 32;
#pragma unroll
  for (int q = 0; q < 4; ++q) {
    int r = ty + q * 8;
    t[r][tx] = in[(long)(r0 + r) * ldi + c0 + tx];
  }
  __syncthreads();
#pragma unroll
  for (int q = 0; q < 4; ++q) {
    int r = ty + q * 8;
    out[(long)(c0 + r) * ldo + r0 + tx] = f2bf(t[tx][r]);
  }
}

// bf16 batched transpose (for V -> V^T per (b,h))
__global__ __launch_bounds__(256) void transpose_b2b(const unsigned short* __restrict__ in,
                                                     unsigned short* __restrict__ out,
                                                     int ldi, int ldo, long i1, long i2,
                                                     long o1, long o2, int hdiv) {
  __shared__ unsigned short t[32][33];
  const int z = blockIdx.z;
  in += (long)(z / hdiv) * i1 + (long)(z % hdiv) * i2;
  out += (long)(z / hdiv) * o1 + (long)(z % hdiv) * o2;
  const int tx = threadIdx.x & 31, ty = threadIdx.x >> 5;
  const int r0 = blockIdx.y * 32, c0 = blockIdx.x * 32;
#pragma unroll
  for (int q = 0; q < 4; ++q) {
    int r = ty + q * 8;
    t[r][tx] = in[(long)(r0 + r) * ldi + c0 + tx];
  }
  __syncthreads();
#pragma unroll
  for (int q = 0; q < 4; ++q) {
    int r = ty + q * 8;
    out[(long)(c0 + r) * ldo + r0 + tx] = t[tx][r];
  }
}

// ---------------------------------------------------------------------------
// out = xin + LayerNorm(sum_j y[j*ystr] + ybias)*g + be   (row 512)
// ---------------------------------------------------------------------------
template <bool WB, int NS>
__global__ __launch_bounds__(256) void ln_res(const float* __restrict__ xin,
                                              const float* __restrict__ y, long ystr,
                                              const float* __restrict__ ybias,
                                              const float* __restrict__ g,
                                              const float* __restrict__ be,
                                              float* __restrict__ xo,
                                              unsigned short* __restrict__ xob) {
  const int row = blockIdx.x, tid = threadIdx.x, lane = tid & 63, wv = tid >> 6;
  const long base = (long)row * 512 + tid * 2;
  const int c = tid * 2;
  float2 v = *(const float2*)&y[base];
#pragma unroll
  for (int j = 1; j < NS; ++j) {
    float2 u = *(const float2*)&y[base + j * ystr];
    v.x += u.x;
    v.y += u.y;
  }
  v.x += ybias[c];
  v.y += ybias[c + 1];
  float s1 = v.x + v.y, s2 = v.x * v.x + v.y * v.y;
  for (int o = 32; o; o >>= 1) {
    s1 += __shfl_xor(s1, o);
    s2 += __shfl_xor(s2, o);
  }
  __shared__ float red[4][2];
  if (lane == 0) {
    red[wv][0] = s1;
    red[wv][1] = s2;
  }
  __syncthreads();
  s1 = red[0][0] + red[1][0] + red[2][0] + red[3][0];
  s2 = red[0][1] + red[1][1] + red[2][1] + red[3][1];
  const float mu = s1 * (1.f / 512.f);
  const float rstd = rsqrtf(s2 * (1.f / 512.f) - mu * mu + 1e-5f);
  float2 xv = *(const float2*)&xin[base];
  float o0 = xv.x + (v.x - mu) * rstd * g[c] + be[c];
  float o1 = xv.y + (v.y - mu) * rstd * g[c + 1] + be[c + 1];
  float2 ov;
  ov.x = o0;
  ov.y = o1;
  *(float2*)&xo[base] = ov;
  if constexpr (WB) {
    unsigned pk = (unsigned)f2bf(o0) | ((unsigned)f2bf(o1) << 16);
    *(unsigned*)&xob[base] = pk;
  }
}

// ---------------------------------------------------------------------------
extern "C" void kernel_launch(void* const* d_in, const int* in_sizes, int n_in,
                              void* d_out, int out_size, void* d_ws, size_t ws_size,
                              hipStream_t stream) {
  const int B = 8, S = 1024, D = 512, H = 8, F = 2048;
  const int BS = B * S;  // 8192 rows
  const int N3 = 3 * D;  // 1536

  const float* x = (const float*)d_in[0];
  const float* Wq = (const float*)d_in[1];
  const float* bq = (const float*)d_in[2];
  const float* Wk = (const float*)d_in[3];
  const float* bk = (const float*)d_in[4];
  const float* Wv = (const float*)d_in[5];
  const float* bv = (const float*)d_in[6];
  const float* Wo = (const float*)d_in[7];
  const float* bo = (const float*)d_in[8];
  const float* g1 = (const float*)d_in[9];
  const float* be1 = (const float*)d_in[10];
  const float* W1 = (const float*)d_in[11];
  const float* b1 = (const float*)d_in[12];
  const float* W2 = (const float*)d_in[13];
  const float* b2 = (const float*)d_in[14];
  const float* g2 = (const float*)d_in[15];
  const float* be2 = (const float*)d_in[16];
  float* out = (float*)d_out;

  char* w = (char*)d_ws;
  size_t off = 0;
  auto alloc = [&](size_t bytes) -> void* {
    void* p = w + off;
    off += bytes;
    off = (off + 255) & ~(size_t)255;
    return p;
  };

  unsigned short* xb = (unsigned short*)alloc((size_t)BS * D * 2);
  unsigned short* Wqkvt = (unsigned short*)alloc((size_t)N3 * D * 2);
  unsigned short* Wot = (unsigned short*)alloc((size_t)D * D * 2);
  unsigned short* W1t = (unsigned short*)alloc((size_t)F * D * 2);
  unsigned short* W2t = (unsigned short*)alloc((size_t)D * F * 2);
  float* bqkv = (float*)alloc((size_t)N3 * 4);
  unsigned short* QKVb = (unsigned short*)alloc((size_t)BS * N3 * 2);
  unsigned short* Vt = (unsigned short*)alloc((size_t)BS * D * 2);
  unsigned short* attn = (unsigned short*)alloc((size_t)BS * D * 2);
  unsigned short* P = (unsigned short*)alloc((size_t)B * H * S * S * 2);  // 128 MiB
  float* x1 = (float*)alloc((size_t)BS * D * 4);
  unsigned short* hb = (unsigned short*)alloc((size_t)BS * F * 2);
  unsigned short* x1b = xb;   // reuse: xb dead after QKV GEMM
  float* yp = (float*)P;      // reuse: P dead after PV GEMM
  const long PSTR = (long)BS * D;

  const long SS = (long)S * S;
  const long HSS = (long)H * SS;
  const long SN3 = (long)S * N3;

  // 1) merged prep: cast x, transpose all weights, concat qkv bias
  prep_all<<<7174, 256, 0, stream>>>(x, xb, Wq, Wk, Wv, Wo, W1, W2,
                                     Wqkvt, Wot, W1t, W2t, bq, bk, bv, bqkv);

  // 2) QKV: A=Wqkvt (M=1536), Bt=xb (N=8192) -> QKVb[xrow][n] transposed-store
  gemm_bt<2, 2, 1, true><<<dim3(N3 / 128, BS / 128, 1), 256, 0, stream>>>(
      Wqkvt, xb, bqkv, QKVb, D, D, D, N3, 0, 0, 0, 0, 0, 0, 1, 1.f);

  // 3) V -> Vt[(b,h), d, s]
  transpose_b2b<<<dim3(2, 32, 64), 256, 0, stream>>>(
      QKVb + 1024, Vt, N3, S, SN3, 64, (long)8 * 64 * S, (long)64 * S, 8);

  // 4) scores: A=K-side, Bt=Q-side -> P[q][k] = (QK^T)/16 transposed-store
  gemm_bt<2, 2, 0, true><<<dim3(S / 128, S / 128, B * H), 256, 0, stream>>>(
      QKVb + 512, QKVb, nullptr, P, 64, N3, N3, S,
      SN3, 64, SN3, 64, HSS, SS, H, 1.f / 16.f);

  // 5) entmax-1.5 per row, in place (2 rows/wave)
  entmax_rows<<<(B * H * S) / 8, 256, 0, stream>>>(P);

  // 6) PV: A=Vt (M=64 d), Bt=P (N=1024 q) -> attn[q][h*64+d] transposed-store
  gemm_bt<1, 4, 0, true><<<dim3(1, S / 256, B * H), 256, 0, stream>>>(
      Vt, P, nullptr, attn, S, S, S, D,
      (long)8 * 64 * S, (long)64 * S, HSS, SS, (long)S * D, 64, H, 1.f);

  // 7) Wo: A=Wot (M=512), Bt=attn, split-K x2 -> yp[xrow][dout] float4 stores
  gemm_bt<2, 2, 0, false><<<dim3(D / 128, BS / 128, 2), 256, 0, stream>>>(
      Wot, attn, nullptr, yp, D / 2, D, D, D, 0, D / 2, 0, D / 2, 0, PSTR, 2, 1.f);

  // 8) x1 = x + LN(y0+y1+bo)*g1 + be1
  ln_res<true, 2><<<BS, 256, 0, stream>>>(x, yp, PSTR, bo, g1, be1, x1, x1b);

  // 9) W1: A=W1t (M=2048), Bt=x1b -> hb[xrow][f] = mish(...), transposed-store
  gemm_bt<2, 2, 2, true><<<dim3(F / 128, BS / 128, 1), 256, 0, stream>>>(
      W1t, x1b, b1, hb, D, D, D, F, 0, 0, 0, 0, 0, 0, 1, 1.f);

  // 10) W2: A=W2t (M=512), Bt=hb, split-K x2 -> yp float4 stores
  gemm_bt<2, 2, 0, false><<<dim3(D / 128, BS / 128, 2), 256, 0, stream>>>(
      W2t, hb, nullptr, yp, F / 2, F, F, D, 0, F / 2, 0, F / 2, 0, PSTR, 2, 1.f);

  // 11) out = x1 + LN(y0+y1+b2)*g2 + be2
  ln_res<false, 2><<<BS, 256, 0, stream>>>(x1, yp, PSTR, b2, g2, be2, out, nullptr);
}